// Round 3
// baseline (328.942 us; speedup 1.0000x reference)
//
#include <hip/hip_runtime.h>

#define ZN 131072          // B*H*W rows
#define DD 64              // embedding dim
#define KK 1024            // codebook entries
#define BSTRIDE 262144     // 64*64*64 (per-batch stride in z)
#define DSTRIDE 4096       // per-d stride in z (H*W)
#define ZQ_ELEMS 8388608   // 32*64*64*64

// ---- workspace layout ----
// [0,8)                double   loss accumulator
// [8,12)               unsigned flagged-row count
// [16,4112)            float    csq32[1024]    (numpy-emulated fp32)
// [4112,528400)        float    zsq32[131072]  (numpy-emulated fp32)
// [528400,1052688)     int      worklist[131072]
// [2363408,2625552)    ushort   cbB[64][2][2][64][8]  bf16 hi/lo B-fragments
#define WS_CSQ_OFF   16
#define WS_ZSQ_OFF   4112
#define WS_WORK_OFF  528400
#define WS_CBB_OFF   2363408

#define RF_CAND 16

typedef __attribute__((ext_vector_type(8))) short short8;
typedef __attribute__((ext_vector_type(4))) float f32x4;

// round-to-nearest-even fp32 -> bf16 (data has no NaN/Inf)
__device__ __forceinline__ unsigned short f2bf_rne(float x) {
    unsigned u = __float_as_uint(x);
    return (unsigned short)((u + 0x7fffu + ((u >> 16) & 1u)) >> 16);
}

// numpy-emulated fp32 sum of a[i]^2 over 64 elems (pairwise, 8 accumulators).
__device__ __forceinline__ float np_sumsq64(const float* a) {
    float r0 = __fmul_rn(a[0], a[0]), r1 = __fmul_rn(a[1], a[1]);
    float r2 = __fmul_rn(a[2], a[2]), r3 = __fmul_rn(a[3], a[3]);
    float r4 = __fmul_rn(a[4], a[4]), r5 = __fmul_rn(a[5], a[5]);
    float r6 = __fmul_rn(a[6], a[6]), r7 = __fmul_rn(a[7], a[7]);
#pragma unroll
    for (int i = 8; i < 64; i += 8) {
        r0 = __fadd_rn(r0, __fmul_rn(a[i + 0], a[i + 0]));
        r1 = __fadd_rn(r1, __fmul_rn(a[i + 1], a[i + 1]));
        r2 = __fadd_rn(r2, __fmul_rn(a[i + 2], a[i + 2]));
        r3 = __fadd_rn(r3, __fmul_rn(a[i + 3], a[i + 3]));
        r4 = __fadd_rn(r4, __fmul_rn(a[i + 4], a[i + 4]));
        r5 = __fadd_rn(r5, __fmul_rn(a[i + 5], a[i + 5]));
        r6 = __fadd_rn(r6, __fmul_rn(a[i + 6], a[i + 6]));
        r7 = __fadd_rn(r7, __fmul_rn(a[i + 7], a[i + 7]));
    }
    return __fadd_rn(__fadd_rn(__fadd_rn(r0, r1), __fadd_rn(r2, r3)),
                     __fadd_rn(__fadd_rn(r4, r5), __fadd_rn(r6, r7)));
}

__global__ __launch_bounds__(256) void vq_csq(const float* __restrict__ cb,
                                              float* __restrict__ csq) {
    int k = blockIdx.x * 256 + threadIdx.x;
    csq[k] = np_sumsq64(cb + k * DD);
}

// Pre-fragment codebook into bf16 hi/lo MFMA B-operand layout.
// B frag for v_mfma_f32_16x16x32_bf16: col = lane&15, k = (lane>>4)*8 + j.
__global__ __launch_bounds__(256) void vq_prep_b(const float* __restrict__ cb,
                                                 unsigned short* __restrict__ cbB) {
    int i = blockIdx.x * 256 + threadIdx.x;  // i = k*64 + d
    int k = i >> 6, d = i & 63;
    float c = cb[i];
    unsigned short hi = f2bf_rne(c);
    float hf = __uint_as_float((unsigned)hi << 16);
    unsigned short lo = f2bf_rne(c - hf);
    int ct = k >> 4, col = k & 15;
    int s = d >> 5, lg = (d >> 3) & 3, j = d & 7;
    int lane = col + 16 * lg;
    int base = ct * 2048 + s * 512 + lane * 8 + j;
    cbB[base] = hi;          // h = 0
    cbB[base + 1024] = lo;   // h = 1
}

// numpy-emulated fp32 ||z||^2 per row (needed by refine).
__global__ __launch_bounds__(256) void vq_zsq(const float* __restrict__ z,
                                              float* __restrict__ zsq32) {
    int n = blockIdx.x * 256 + threadIdx.x;
    int b = n >> 12, p = n & 4095;
    const float* zp = z + (size_t)b * BSTRIDE + p;
    float r[8];
#pragma unroll
    for (int j = 0; j < 8; ++j) {
        float v = zp[(size_t)j * DSTRIDE];
        r[j] = __fmul_rn(v, v);
    }
#pragma unroll
    for (int i = 8; i < 64; i += 8)
#pragma unroll
        for (int j = 0; j < 8; ++j) {
            float v = zp[(size_t)(i + j) * DSTRIDE];
            r[j] = __fadd_rn(r[j], __fmul_rn(v, v));
        }
    zsq32[n] = __fadd_rn(__fadd_rn(__fadd_rn(r[0], r[1]), __fadd_rn(r[2], r[3])),
                         __fadd_rn(__fadd_rn(r[4], r[5]), __fadd_rn(r[6], r[7])));
}

// dist computation shared by scan and refine: two independent 3-chains.
// products: Hh(d0-31), Hh(d32-63), Lh(d0-31) | Hl(d0-31), Hl(d32-63), Lh(d32-63)
#define MFMA_DIST(P, Q, A_H0, A_H1, A_L0, A_L1, B0, B1, B2, B3)               \
    P = __builtin_amdgcn_mfma_f32_16x16x32_bf16(A_H0, B0, P, 0, 0, 0);        \
    Q = __builtin_amdgcn_mfma_f32_16x16x32_bf16(A_H0, B2, Q, 0, 0, 0);        \
    P = __builtin_amdgcn_mfma_f32_16x16x32_bf16(A_H1, B1, P, 0, 0, 0);        \
    Q = __builtin_amdgcn_mfma_f32_16x16x32_bf16(A_H1, B3, Q, 0, 0, 0);        \
    P = __builtin_amdgcn_mfma_f32_16x16x32_bf16(A_L0, B0, P, 0, 0, 0);        \
    Q = __builtin_amdgcn_mfma_f32_16x16x32_bf16(A_L1, B1, Q, 0, 0, 0);

// -------- MFMA bf16^3 single-phase argmin scan --------
// block = 64 rows x 4 waves; wave wv scans codes [wv*256, wv*256+256).
// Tracks (min1, min2, best) per row; rows with min2-min1 < 2e-4 are flagged
// into a compact worklist for exact refinement. Error budget: MFMA dist err
// ~4e-6, reference-fp32 rounding noise ~2e-5, so a gap >= 2e-4 can never flip.
__global__ __attribute__((amdgpu_waves_per_eu(2, 2))) __launch_bounds__(256)
void vq_scan(const float* __restrict__ z,
             const unsigned short* __restrict__ cbB,
             const float* __restrict__ csq,
             float* __restrict__ idxf_out,
             unsigned* __restrict__ wcount,
             int* __restrict__ worklist) {
    __shared__ __align__(16) unsigned short aFrag[4][2][2][64][8];  // [rt][s][h][lane][j]
    __shared__ float scsq[1024];
    __shared__ float smin1[4][64], smin2[4][64];
    __shared__ int sbest[4][64];

    int t = threadIdx.x;
    int n0 = blockIdx.x * 64;
    int b = n0 >> 12, p0 = n0 & 4095;   // 64 | 4096 -> no batch crossing in block

    for (int i = t; i < 1024; i += 256) scsq[i] = csq[i];

    {   // stage z tile: thread t loads row r = t&63, d-groups g = 2*(t>>6)+{0,1}
        int r = t & 63, gb = t >> 6;
        const float* zp = z + (size_t)b * BSTRIDE + p0 + r;
#pragma unroll
        for (int gg = 0; gg < 2; ++gg) {
            int g = (gb << 1) | gg;  // d in [8g, 8g+8)
            short8 hi8, lo8;
#pragma unroll
            for (int i2 = 0; i2 < 8; ++i2) {
                float v = zp[(size_t)(8 * g + i2) * DSTRIDE];  // coalesced across lanes
                unsigned short h = f2bf_rne(v);
                float hf = __uint_as_float((unsigned)h << 16);
                hi8[i2] = (short)h;
                lo8[i2] = (short)f2bf_rne(v - hf);
            }
            int rt = r >> 4, s = g >> 2, lane = (r & 15) + 16 * (g & 3);
            *(short8*)&aFrag[rt][s][0][lane][0] = hi8;
            *(short8*)&aFrag[rt][s][1][lane][0] = lo8;
        }
    }
    __syncthreads();

    int l = t & 63;
    int colcode = l & 15;
    int wv = __builtin_amdgcn_readfirstlane(t >> 6);

    short8 aH[4][2], aL[4][2];  // [rowtile][k-step] — keep register-resident
#pragma unroll
    for (int rt = 0; rt < 4; ++rt)
#pragma unroll
        for (int s = 0; s < 2; ++s) {
            aH[rt][s] = *(const short8*)&aFrag[rt][s][0][l][0];
            aL[rt][s] = *(const short8*)&aFrag[rt][s][1][l][0];
        }

    float m1[4][4], m2[4][4];
    int bst[4][4];
#pragma unroll
    for (int rt = 0; rt < 4; ++rt)
#pragma unroll
        for (int r = 0; r < 4; ++r) {
            m1[rt][r] = 3.4e38f;
            m2[rt][r] = 3.4e38f;
            bst[rt][r] = 0;
        }

    const unsigned short* bpb = cbB + (wv << 4) * 2048 + (l << 3);
    short8 nb0 = *(const short8*)(bpb);
    short8 nb1 = *(const short8*)(bpb + 512);
    short8 nb2 = *(const short8*)(bpb + 1024);
    short8 nb3 = *(const short8*)(bpb + 1536);
    for (int cti = 0; cti < 16; ++cti) {
        short8 b0 = nb0, b1 = nb1, b2 = nb2, b3 = nb3;
        if (cti < 15) {  // double-buffered B prefetch
            const unsigned short* np = bpb + (cti + 1) * 2048;
            nb0 = *(const short8*)(np);
            nb1 = *(const short8*)(np + 512);
            nb2 = *(const short8*)(np + 1024);
            nb3 = *(const short8*)(np + 1536);
        }
        int ct = (wv << 4) + cti;
        float cs = scsq[(ct << 4) + colcode];
        int code = (ct << 4) + colcode;
#pragma unroll
        for (int rt = 0; rt < 4; ++rt) {
            f32x4 p = {0.f, 0.f, 0.f, 0.f}, q = {0.f, 0.f, 0.f, 0.f};
            MFMA_DIST(p, q, aH[rt][0], aH[rt][1], aL[rt][0], aL[rt][1], b0, b1, b2, b3)
#pragma unroll
            for (int r = 0; r < 4; ++r) {
                float dist = fmaf(-2.f, p[r] + q[r], cs);
                bool lt = dist < m1[rt][r];  // strict: ties keep lowest code
                m2[rt][r] = lt ? m1[rt][r] : fminf(m2[rt][r], dist);
                bst[rt][r] = lt ? code : bst[rt][r];
                m1[rt][r] = lt ? dist : m1[rt][r];
            }
        }
    }

    // merge across the 16 lanes (cols) sharing each row: butterfly xor 1,2,4,8
#pragma unroll
    for (int m = 1; m <= 8; m <<= 1) {
#pragma unroll
        for (int rt = 0; rt < 4; ++rt)
#pragma unroll
            for (int r = 0; r < 4; ++r) {
                float o1 = __shfl_xor(m1[rt][r], m, 64);
                float o2 = __shfl_xor(m2[rt][r], m, 64);
                int ob = __shfl_xor(bst[rt][r], m, 64);
                bool take = (o1 < m1[rt][r]) ||
                            (o1 == m1[rt][r] && ob < bst[rt][r]);
                float n2 = take ? fminf(o2, m1[rt][r]) : fminf(m2[rt][r], o1);
                m1[rt][r] = take ? o1 : m1[rt][r];
                bst[rt][r] = take ? ob : bst[rt][r];
                m2[rt][r] = n2;
            }
    }

    // one writer per row-slot into the cross-wave merge arrays
#pragma unroll
    for (int rt = 0; rt < 4; ++rt)
#pragma unroll
        for (int r = 0; r < 4; ++r)
            if ((l & 15) == r) {
                int row = (rt << 4) + ((l >> 4) << 2) + r;
                smin1[wv][row] = m1[rt][r];
                smin2[wv][row] = m2[rt][r];
                sbest[wv][row] = bst[rt][r];
            }
    __syncthreads();

    if (t < 64) {  // wave 0: cross-chunk merge, flag, compact
        float g1 = smin1[0][t], g2 = smin2[0][t];
        int gb = sbest[0][t];
#pragma unroll
        for (int c = 1; c < 4; ++c) {
            float c1 = smin1[c][t];
            if (c1 < g1) {                 // strict: ties keep lower-k chunk
                g2 = fminf(g1, smin2[c][t]);
                gb = sbest[c][t];
                g1 = c1;
            } else {
                g2 = fminf(g2, c1);
            }
        }
        idxf_out[n0 + t] = (float)gb;
        bool flag = (g2 - g1 < 2e-4f);
        unsigned long long mb = __ballot(flag);
        int tot = __popcll(mb);
        unsigned base = 0;
        if (t == 0 && tot) base = atomicAdd(wcount, (unsigned)tot);
        base = __shfl(base, 0, 64);
        if (flag) {
            int pre = __popcll(mb & ((1ull << t) - 1ull));
            worklist[base + pre] = n0 + t;
        }
    }
}

// -------- flagged-row exact refine (self-contained) --------
// Per 64 gathered flagged rows: MFMA pass A -> per-row gmin; pass B (bit-
// identical dists) -> emit candidates within 2e-4 of gmin; fp64 reference-
// emulated distance on candidates only; tie-break lowest k; write idxf.
// Overflow (>16 candidates, adversarial ties) falls back to all 1024 codes.
__global__ __attribute__((amdgpu_waves_per_eu(2, 2))) __launch_bounds__(256)
void vq_refine(const float* __restrict__ z,
               const unsigned short* __restrict__ cbB,
               const float* __restrict__ cb,
               const float* __restrict__ csq,
               const float* __restrict__ zsq32,
               const unsigned* __restrict__ wcount,
               const int* __restrict__ worklist,
               float* __restrict__ idxf) {
    __shared__ __align__(16) unsigned short aFrag[4][2][2][64][8];
    __shared__ float scsq[1024];
    __shared__ float smin[4][64];
    __shared__ float gmin[64];
    __shared__ int rown[64];
    __shared__ int candCnt[64];
    __shared__ unsigned short candK[64][RF_CAND];
    __shared__ unsigned long long rpack[64];

    int t = threadIdx.x;
    int l = t & 63;
    int colcode = l & 15;
    int wv = __builtin_amdgcn_readfirstlane(t >> 6);

    for (int i = t; i < 1024; i += 256) scsq[i] = csq[i];

    unsigned cnt = *wcount;
    for (unsigned c0 = blockIdx.x * 64u; c0 < cnt; c0 += gridDim.x * 64u) {
        int nrows = (int)((cnt - c0 < 64u) ? (cnt - c0) : 64u);
        if (t < 64) {
            rown[t] = (t < nrows) ? worklist[c0 + t] : worklist[c0];  // pad: dup row 0
            candCnt[t] = 0;
            rpack[t] = ~0ull;
        }
        __syncthreads();

        {   // stage gathered z rows into A-fragment layout
            int r = t & 63, gb = t >> 6;
            int n = rown[r];
            int b = n >> 12, p = n & 4095;
            const float* zp = z + (size_t)b * BSTRIDE + p;
#pragma unroll
            for (int gg = 0; gg < 2; ++gg) {
                int g = (gb << 1) | gg;
                short8 hi8, lo8;
#pragma unroll
                for (int i2 = 0; i2 < 8; ++i2) {
                    float v = zp[(size_t)(8 * g + i2) * DSTRIDE];
                    unsigned short h = f2bf_rne(v);
                    float hf = __uint_as_float((unsigned)h << 16);
                    hi8[i2] = (short)h;
                    lo8[i2] = (short)f2bf_rne(v - hf);
                }
                int rt = r >> 4, s = g >> 2, lane = (r & 15) + 16 * (g & 3);
                *(short8*)&aFrag[rt][s][0][lane][0] = hi8;
                *(short8*)&aFrag[rt][s][1][lane][0] = lo8;
            }
        }
        __syncthreads();

        short8 aH[4][2], aL[4][2];
#pragma unroll
        for (int rt = 0; rt < 4; ++rt)
#pragma unroll
            for (int s = 0; s < 2; ++s) {
                aH[rt][s] = *(const short8*)&aFrag[rt][s][0][l][0];
                aL[rt][s] = *(const short8*)&aFrag[rt][s][1][l][0];
            }

        const unsigned short* bpb = cbB + (wv << 4) * 2048 + (l << 3);

        // ---- pass A: per-row min ----
        float m1[4][4];
#pragma unroll
        for (int rt = 0; rt < 4; ++rt)
#pragma unroll
            for (int r = 0; r < 4; ++r) m1[rt][r] = 3.4e38f;

        for (int cti = 0; cti < 16; ++cti) {
            const unsigned short* bp = bpb + cti * 2048;
            short8 b0 = *(const short8*)(bp);
            short8 b1 = *(const short8*)(bp + 512);
            short8 b2 = *(const short8*)(bp + 1024);
            short8 b3 = *(const short8*)(bp + 1536);
            int ct = (wv << 4) + cti;
            float cs = scsq[(ct << 4) + colcode];
#pragma unroll
            for (int rt = 0; rt < 4; ++rt) {
                f32x4 p = {0.f, 0.f, 0.f, 0.f}, q = {0.f, 0.f, 0.f, 0.f};
                MFMA_DIST(p, q, aH[rt][0], aH[rt][1], aL[rt][0], aL[rt][1], b0, b1, b2, b3)
#pragma unroll
                for (int r = 0; r < 4; ++r)
                    m1[rt][r] = fminf(m1[rt][r], fmaf(-2.f, p[r] + q[r], cs));
            }
        }
#pragma unroll
        for (int m = 1; m <= 8; m <<= 1)
#pragma unroll
            for (int rt = 0; rt < 4; ++rt)
#pragma unroll
                for (int r = 0; r < 4; ++r)
                    m1[rt][r] = fminf(m1[rt][r], __shfl_xor(m1[rt][r], m, 64));
#pragma unroll
        for (int rt = 0; rt < 4; ++rt)
#pragma unroll
            for (int r = 0; r < 4; ++r)
                if ((l & 15) == r)
                    smin[wv][(rt << 4) + ((l >> 4) << 2) + r] = m1[rt][r];
        __syncthreads();
        if (t < 64)
            gmin[t] = fminf(fminf(smin[0][t], smin[1][t]),
                            fminf(smin[2][t], smin[3][t]));
        __syncthreads();

        // ---- pass B: bit-identical rescan, candidate emission ----
        for (int cti = 0; cti < 16; ++cti) {
            const unsigned short* bp = bpb + cti * 2048;
            short8 b0 = *(const short8*)(bp);
            short8 b1 = *(const short8*)(bp + 512);
            short8 b2 = *(const short8*)(bp + 1024);
            short8 b3 = *(const short8*)(bp + 1536);
            int ct = (wv << 4) + cti;
            float cs = scsq[(ct << 4) + colcode];
            unsigned code = (unsigned)((ct << 4) + colcode);
#pragma unroll
            for (int rt = 0; rt < 4; ++rt) {
                f32x4 p = {0.f, 0.f, 0.f, 0.f}, q = {0.f, 0.f, 0.f, 0.f};
                MFMA_DIST(p, q, aH[rt][0], aH[rt][1], aL[rt][0], aL[rt][1], b0, b1, b2, b3)
#pragma unroll
                for (int r = 0; r < 4; ++r) {
                    float dist = fmaf(-2.f, p[r] + q[r], cs);
                    int row = (rt << 4) + ((l >> 4) << 2) + r;
                    if (dist < gmin[row] + 2e-4f) {
                        int pos = atomicAdd(&candCnt[row], 1);
                        if (pos < RF_CAND) candK[row][pos] = (unsigned short)code;
                    }
                }
            }
        }
        __syncthreads();

        // ---- fp64 reference-emulated distance on candidates ----
        for (int i = t; i < 64 * RF_CAND; i += 256) {
            int r = i >> 4, sIdx = i & (RF_CAND - 1);
            int cc = candCnt[r];
            if (r < nrows && cc <= RF_CAND && sIdx < cc) {
                unsigned k = candK[r][sIdx];
                int n = rown[r];
                int b = n >> 12, p = n & 4095;
                const float* zp = z + (size_t)b * BSTRIDE + p;
                const float* cp = cb + k * DD;
                double a0 = 0.0, a1 = 0.0, a2 = 0.0, a3 = 0.0;
#pragma unroll
                for (int d = 0; d < DD; d += 4) {
                    a0 = fma((double)zp[(size_t)(d + 0) * DSTRIDE], (double)cp[d + 0], a0);
                    a1 = fma((double)zp[(size_t)(d + 1) * DSTRIDE], (double)cp[d + 1], a1);
                    a2 = fma((double)zp[(size_t)(d + 2) * DSTRIDE], (double)cp[d + 2], a2);
                    a3 = fma((double)zp[(size_t)(d + 3) * DSTRIDE], (double)cp[d + 3], a3);
                }
                double dot = (a0 + a1) + (a2 + a3);
                float twoC = (float)(2.0 * dot);
                float dist = __fsub_rn(__fadd_rn(zsq32[n], csq[k]), twoC);
                unsigned ub = __float_as_uint(dist);
                ub = (ub & 0x80000000u) ? ~ub : (ub | 0x80000000u);
                unsigned long long pk = ((unsigned long long)ub << 32) | k;
                atomicMin(&rpack[r], pk);
            }
        }
        // overflow rows (ultra-rare, adversarial ties): all 1024 codes
        for (int r = 0; r < 64; ++r) {
            if (candCnt[r] > RF_CAND && r < nrows) {
                int n = rown[r];
                int b = n >> 12, p = n & 4095;
                const float* zp = z + (size_t)b * BSTRIDE + p;
                for (unsigned k = (unsigned)t; k < 1024u; k += 256u) {
                    const float* cp = cb + k * DD;
                    double a0 = 0.0, a1 = 0.0, a2 = 0.0, a3 = 0.0;
#pragma unroll
                    for (int d = 0; d < DD; d += 4) {
                        a0 = fma((double)zp[(size_t)(d + 0) * DSTRIDE], (double)cp[d + 0], a0);
                        a1 = fma((double)zp[(size_t)(d + 1) * DSTRIDE], (double)cp[d + 1], a1);
                        a2 = fma((double)zp[(size_t)(d + 2) * DSTRIDE], (double)cp[d + 2], a2);
                        a3 = fma((double)zp[(size_t)(d + 3) * DSTRIDE], (double)cp[d + 3], a3);
                    }
                    double dot = (a0 + a1) + (a2 + a3);
                    float twoC = (float)(2.0 * dot);
                    float dist = __fsub_rn(__fadd_rn(zsq32[n], csq[k]), twoC);
                    unsigned ub = __float_as_uint(dist);
                    ub = (ub & 0x80000000u) ? ~ub : (ub | 0x80000000u);
                    unsigned long long pk = ((unsigned long long)ub << 32) | k;
                    atomicMin(&rpack[r], pk);
                }
            }
        }
        __syncthreads();

        if (t < nrows)
            idxf[rown[t]] = (float)(unsigned)(rpack[t] & 0xFFFFFFFFull);
        __syncthreads();  // before next chunk reuses LDS
    }
}

// -------- gather z_q + loss partial reduction --------
__global__ __launch_bounds__(256) void vq_gather_loss(const float* __restrict__ z,
                                                      const float* __restrict__ cb,
                                                      const float* __restrict__ idxf,
                                                      float* __restrict__ zq_out,
                                                      double* __restrict__ acc) {
    int n = blockIdx.x * 256 + threadIdx.x;
    int b = n >> 12, p = n & 4095;
    const float* zp = z + (size_t)b * BSTRIDE + p;
    float* qp = zq_out + (size_t)b * BSTRIDE + p;
    int k = (int)idxf[n];
    const float* c = cb + k * DD;

    float s = 0.f;
#pragma unroll
    for (int d = 0; d < DD; ++d) {
        float q = c[d];
        float diff = q - zp[(size_t)d * DSTRIDE];
        s = fmaf(diff, diff, s);
        qp[(size_t)d * DSTRIDE] = q;  // z_q_st == z_q numerically
    }

#pragma unroll
    for (int off = 32; off; off >>= 1) s += __shfl_down(s, off, 64);
    __shared__ float partial[4];
    if ((threadIdx.x & 63) == 0) partial[threadIdx.x >> 6] = s;
    __syncthreads();
    if (threadIdx.x == 0) {
        float t = (partial[0] + partial[1]) + (partial[2] + partial[3]);
        atomicAdd(acc, (double)t);
    }
}

__global__ void vq_finalize(const double* __restrict__ acc, float* __restrict__ loss_out) {
    *loss_out = (float)(1.25 * (*acc) / (double)ZQ_ELEMS);
}

extern "C" void kernel_launch(void* const* d_in, const int* in_sizes, int n_in,
                              void* d_out, int out_size, void* d_ws, size_t ws_size,
                              hipStream_t stream) {
    const float* z = (const float*)d_in[0];
    const float* cb = (const float*)d_in[1];
    float* out = (float*)d_out;

    float* zq_out = out;                   // [0, 8388608)
    float* loss_out = out + ZQ_ELEMS;      // [8388608]
    float* idxf_out = out + ZQ_ELEMS + 1;  // [8388609, +131072)

    char* ws = (char*)d_ws;
    double* acc = (double*)ws;
    unsigned* wcount = (unsigned*)(ws + 8);
    float* csq = (float*)(ws + WS_CSQ_OFF);
    float* zsq32 = (float*)(ws + WS_ZSQ_OFF);
    int* worklist = (int*)(ws + WS_WORK_OFF);
    unsigned short* cbB = (unsigned short*)(ws + WS_CBB_OFF);

    hipMemsetAsync(d_ws, 0, 16, stream);   // acc = 0, wcount = 0

    vq_csq<<<KK / 256, 256, 0, stream>>>(cb, csq);
    vq_prep_b<<<KK * DD / 256, 256, 0, stream>>>(cb, cbB);
    vq_zsq<<<ZN / 256, 256, 0, stream>>>(z, zsq32);
    vq_scan<<<ZN / 64, 256, 0, stream>>>(z, cbB, csq, idxf_out, wcount, worklist);
    vq_refine<<<512, 256, 0, stream>>>(z, cbB, cb, csq, zsq32, wcount, worklist, idxf_out);
    vq_gather_loss<<<ZN / 256, 256, 0, stream>>>(z, cb, idxf_out, zq_out, acc);
    vq_finalize<<<1, 1, 0, stream>>>(acc, loss_out);
}

// Round 4
// 257.477 us; speedup vs baseline: 1.2776x; 1.2776x over previous
//
#include <hip/hip_runtime.h>

#define ZN 131072          // B*H*W rows
#define DD 64              // embedding dim
#define KK 1024            // codebook entries
#define BSTRIDE 262144     // 64*64*64 (per-batch stride in z)
#define DSTRIDE 4096       // per-d stride in z (H*W)
#define ZQ_ELEMS 8388608   // 32*64*64*64

// ---- workspace layout ----
// [0,8)                double   loss accumulator
// [8,12)               unsigned flagged-row count
// [16,4112)            float    csq32[1024]    (numpy-emulated fp32)
// [4112,528400)        float    zsq32[131072]  (numpy-emulated fp32)
// [528400,1052688)     int      worklist[131072]
// [1052688,1576976)    float    gminbuf[131072] (per-row MFMA-exact min dist)
// [2363408,2625552)    ushort   cbB[64][2][2][64][8]  bf16 hi/lo B-fragments
#define WS_CSQ_OFF   16
#define WS_ZSQ_OFF   4112
#define WS_WORK_OFF  528400
#define WS_GMIN_OFF  1052688
#define WS_CBB_OFF   2363408

#define RF_CAND 16

typedef __attribute__((ext_vector_type(8))) short short8;
typedef __attribute__((ext_vector_type(4))) float f32x4;

// round-to-nearest-even fp32 -> bf16 (data has no NaN/Inf)
__device__ __forceinline__ unsigned short f2bf_rne(float x) {
    unsigned u = __float_as_uint(x);
    return (unsigned short)((u + 0x7fffu + ((u >> 16) & 1u)) >> 16);
}

// numpy-emulated fp32 sum of a[i]^2 over 64 elems (pairwise, 8 accumulators).
__device__ __forceinline__ float np_sumsq64(const float* a) {
    float r0 = __fmul_rn(a[0], a[0]), r1 = __fmul_rn(a[1], a[1]);
    float r2 = __fmul_rn(a[2], a[2]), r3 = __fmul_rn(a[3], a[3]);
    float r4 = __fmul_rn(a[4], a[4]), r5 = __fmul_rn(a[5], a[5]);
    float r6 = __fmul_rn(a[6], a[6]), r7 = __fmul_rn(a[7], a[7]);
#pragma unroll
    for (int i = 8; i < 64; i += 8) {
        r0 = __fadd_rn(r0, __fmul_rn(a[i + 0], a[i + 0]));
        r1 = __fadd_rn(r1, __fmul_rn(a[i + 1], a[i + 1]));
        r2 = __fadd_rn(r2, __fmul_rn(a[i + 2], a[i + 2]));
        r3 = __fadd_rn(r3, __fmul_rn(a[i + 3], a[i + 3]));
        r4 = __fadd_rn(r4, __fmul_rn(a[i + 4], a[i + 4]));
        r5 = __fadd_rn(r5, __fmul_rn(a[i + 5], a[i + 5]));
        r6 = __fadd_rn(r6, __fmul_rn(a[i + 6], a[i + 6]));
        r7 = __fadd_rn(r7, __fmul_rn(a[i + 7], a[i + 7]));
    }
    return __fadd_rn(__fadd_rn(__fadd_rn(r0, r1), __fadd_rn(r2, r3)),
                     __fadd_rn(__fadd_rn(r4, r5), __fadd_rn(r6, r7)));
}

__global__ __launch_bounds__(256) void vq_csq(const float* __restrict__ cb,
                                              float* __restrict__ csq) {
    int k = blockIdx.x * 256 + threadIdx.x;
    csq[k] = np_sumsq64(cb + k * DD);
}

// Pre-fragment codebook into bf16 hi/lo MFMA B-operand layout.
// B frag for v_mfma_f32_16x16x32_bf16: col = lane&15, k = (lane>>4)*8 + j.
__global__ __launch_bounds__(256) void vq_prep_b(const float* __restrict__ cb,
                                                 unsigned short* __restrict__ cbB) {
    int i = blockIdx.x * 256 + threadIdx.x;  // i = k*64 + d
    int k = i >> 6, d = i & 63;
    float c = cb[i];
    unsigned short hi = f2bf_rne(c);
    float hf = __uint_as_float((unsigned)hi << 16);
    unsigned short lo = f2bf_rne(c - hf);
    int ct = k >> 4, col = k & 15;
    int s = d >> 5, lg = (d >> 3) & 3, j = d & 7;
    int lane = col + 16 * lg;
    int base = ct * 2048 + s * 512 + lane * 8 + j;
    cbB[base] = hi;          // h = 0
    cbB[base + 1024] = lo;   // h = 1
}

// numpy-emulated fp32 ||z||^2 per row (needed by refine).
__global__ __launch_bounds__(256) void vq_zsq(const float* __restrict__ z,
                                              float* __restrict__ zsq32) {
    int n = blockIdx.x * 256 + threadIdx.x;
    int b = n >> 12, p = n & 4095;
    const float* zp = z + (size_t)b * BSTRIDE + p;
    float r[8];
#pragma unroll
    for (int j = 0; j < 8; ++j) {
        float v = zp[(size_t)j * DSTRIDE];
        r[j] = __fmul_rn(v, v);
    }
#pragma unroll
    for (int i = 8; i < 64; i += 8)
#pragma unroll
        for (int j = 0; j < 8; ++j) {
            float v = zp[(size_t)(i + j) * DSTRIDE];
            r[j] = __fadd_rn(r[j], __fmul_rn(v, v));
        }
    zsq32[n] = __fadd_rn(__fadd_rn(__fadd_rn(r[0], r[1]), __fadd_rn(r[2], r[3])),
                         __fadd_rn(__fadd_rn(r[4], r[5]), __fadd_rn(r[6], r[7])));
}

// dist computation shared by scan and refine: two independent 3-chains.
// sum = Hh(d0-31)+Hh(d32-63)+Lh(d0-31) | Hl(d0-31)+Hl(d32-63)+Lh(d32-63)
#define MFMA_DIST(P, Q, A_H0, A_H1, A_L0, A_L1, B0, B1, B2, B3)               \
    P = __builtin_amdgcn_mfma_f32_16x16x32_bf16(A_H0, B0, P, 0, 0, 0);        \
    Q = __builtin_amdgcn_mfma_f32_16x16x32_bf16(A_H0, B2, Q, 0, 0, 0);        \
    P = __builtin_amdgcn_mfma_f32_16x16x32_bf16(A_H1, B1, P, 0, 0, 0);        \
    Q = __builtin_amdgcn_mfma_f32_16x16x32_bf16(A_H1, B3, Q, 0, 0, 0);        \
    P = __builtin_amdgcn_mfma_f32_16x16x32_bf16(A_L0, B0, P, 0, 0, 0);        \
    Q = __builtin_amdgcn_mfma_f32_16x16x32_bf16(A_L1, B1, Q, 0, 0, 0);

// -------- MFMA bf16^3 single-phase argmin scan, wave-per-row-tile --------
// block = 64 rows = 4 waves; wave w owns rows [16w,16w+16) and scans ALL 1024
// codes (no cross-wave merge). Low per-wave VGPR state -> 4-6 waves/SIMD.
// Barrier every 8 ct keeps the 4 waves phase-locked so their identical B-frag
// read streams share L1 (32KB working set). Writes per-row min to gminbuf;
// rows with min2-min1 < 2e-4 are flagged (MFMA dist err ~4e-6, reference-fp32
// rounding noise ~2e-5: a gap >= 2e-4 can never flip).
__global__ __launch_bounds__(256)
void vq_scan(const float* __restrict__ z,
             const unsigned short* __restrict__ cbB,
             const float* __restrict__ csq,
             float* __restrict__ idxf_out,
             float* __restrict__ gminbuf,
             unsigned* __restrict__ wcount,
             int* __restrict__ worklist) {
    __shared__ __align__(16) unsigned short aFrag[4][2][2][64][8];  // [rt][s][h][lane][j]
    __shared__ float scsq[1024];
    __shared__ float rmin1[64], rmin2[64];
    __shared__ int rbest[64];

    int t = threadIdx.x;
    int n0 = blockIdx.x * 64;
    int b = n0 >> 12, p0 = n0 & 4095;   // 64 | 4096 -> no batch crossing in block

    for (int i = t; i < 1024; i += 256) scsq[i] = csq[i];

    {   // stage z tile: thread t loads row r = t&63, d-groups g = 2*(t>>6)+{0,1}
        int r = t & 63, gb = t >> 6;
        const float* zp = z + (size_t)b * BSTRIDE + p0 + r;
#pragma unroll
        for (int gg = 0; gg < 2; ++gg) {
            int g = (gb << 1) | gg;  // d in [8g, 8g+8)
            short8 hi8, lo8;
#pragma unroll
            for (int i2 = 0; i2 < 8; ++i2) {
                float v = zp[(size_t)(8 * g + i2) * DSTRIDE];  // coalesced across lanes
                unsigned short h = f2bf_rne(v);
                float hf = __uint_as_float((unsigned)h << 16);
                hi8[i2] = (short)h;
                lo8[i2] = (short)f2bf_rne(v - hf);
            }
            int rt = r >> 4, s = g >> 2, lane = (r & 15) + 16 * (g & 3);
            *(short8*)&aFrag[rt][s][0][lane][0] = hi8;
            *(short8*)&aFrag[rt][s][1][lane][0] = lo8;
        }
    }
    __syncthreads();

    int l = t & 63;
    int colcode = l & 15;
    int w = __builtin_amdgcn_readfirstlane(t >> 6);  // wave id = row-tile

    short8 aH0 = *(const short8*)&aFrag[w][0][0][l][0];
    short8 aH1 = *(const short8*)&aFrag[w][1][0][l][0];
    short8 aL0 = *(const short8*)&aFrag[w][0][1][l][0];
    short8 aL1 = *(const short8*)&aFrag[w][1][1][l][0];

    float m1[4], m2[4];
    int bst[4];
#pragma unroll
    for (int r = 0; r < 4; ++r) {
        m1[r] = 3.4e38f;
        m2[r] = 3.4e38f;
        bst[r] = 0;
    }

    for (int ph = 0; ph < 8; ++ph) {
        __syncthreads();  // phase-lock the 4 waves for L1 B-frag reuse
#pragma unroll 2
        for (int c8 = 0; c8 < 8; ++c8) {
            int ct = ph * 8 + c8;
            const unsigned short* bp = cbB + ct * 2048 + (l << 3);
            short8 b0 = *(const short8*)(bp);
            short8 b1 = *(const short8*)(bp + 512);
            short8 b2 = *(const short8*)(bp + 1024);
            short8 b3 = *(const short8*)(bp + 1536);
            float cs = scsq[(ct << 4) + colcode];
            int code = (ct << 4) + colcode;
            f32x4 p = {0.f, 0.f, 0.f, 0.f}, q = {0.f, 0.f, 0.f, 0.f};
            MFMA_DIST(p, q, aH0, aH1, aL0, aL1, b0, b1, b2, b3)
#pragma unroll
            for (int r = 0; r < 4; ++r) {
                float dist = fmaf(-2.f, p[r] + q[r], cs);
                bool lt = dist < m1[r];  // strict: ties keep lowest code
                m2[r] = lt ? m1[r] : fminf(m2[r], dist);
                bst[r] = lt ? code : bst[r];
                m1[r] = lt ? dist : m1[r];
            }
        }
    }

    // merge across the 16 lanes (cols) sharing each row: butterfly xor 1,2,4,8
#pragma unroll
    for (int m = 1; m <= 8; m <<= 1) {
#pragma unroll
        for (int r = 0; r < 4; ++r) {
            float o1 = __shfl_xor(m1[r], m, 64);
            float o2 = __shfl_xor(m2[r], m, 64);
            int ob = __shfl_xor(bst[r], m, 64);
            bool take = (o1 < m1[r]) || (o1 == m1[r] && ob < bst[r]);
            float n2 = take ? fminf(o2, m1[r]) : fminf(m2[r], o1);
            m1[r] = take ? o1 : m1[r];
            bst[r] = take ? ob : bst[r];
            m2[r] = n2;
        }
    }

    // one writer per row (wave covers its 16 rows completely)
#pragma unroll
    for (int r = 0; r < 4; ++r)
        if (colcode == r) {
            int row = (w << 4) + ((l >> 4) << 2) + r;
            rmin1[row] = m1[r];
            rmin2[row] = m2[r];
            rbest[row] = bst[r];
        }
    __syncthreads();

    if (t < 64) {  // wave 0: flag + compact
        float g1 = rmin1[t], g2 = rmin2[t];
        int gb = rbest[t];
        int n = n0 + t;
        idxf_out[n] = (float)gb;
        gminbuf[n] = g1;
        bool flag = (g2 - g1 < 2e-4f);
        unsigned long long mb = __ballot(flag);
        int tot = __popcll(mb);
        unsigned base = 0;
        if (t == 0 && tot) base = atomicAdd(wcount, (unsigned)tot);
        base = __shfl(base, 0, 64);
        if (flag) {
            int pre = __popcll(mb & ((1ull << t) - 1ull));
            worklist[base + pre] = n;
        }
    }
}

// -------- flagged-row exact refine (lean: no pass A, gmin from scan) --------
// Per 64 gathered flagged rows: one MFMA rescan producing bit-identical dists
// (same fragments, same MFMA_DIST macro, same cs) -> candidates within 2e-4 of
// the scan's per-row min; fp64 reference-emulated distance on candidates only;
// tie-break lowest k. Overflow (>16 candidates) falls back to all 1024 codes.
__global__ __launch_bounds__(256)
void vq_refine(const float* __restrict__ z,
               const unsigned short* __restrict__ cbB,
               const float* __restrict__ cb,
               const float* __restrict__ csq,
               const float* __restrict__ zsq32,
               const float* __restrict__ gminbuf,
               const unsigned* __restrict__ wcount,
               const int* __restrict__ worklist,
               float* __restrict__ idxf) {
    __shared__ __align__(16) unsigned short aFrag[4][2][2][64][8];
    __shared__ float scsq[1024];
    __shared__ int rown[64];
    __shared__ float rgminS[64];
    __shared__ int candCnt[64];
    __shared__ unsigned short candK[64][RF_CAND];
    __shared__ unsigned long long rpack[64];

    int t = threadIdx.x;
    int l = t & 63;
    int colcode = l & 15;
    int w = __builtin_amdgcn_readfirstlane(t >> 6);

    for (int i = t; i < 1024; i += 256) scsq[i] = csq[i];

    unsigned cnt = *wcount;
    for (unsigned c0 = blockIdx.x * 64u; c0 < cnt; c0 += gridDim.x * 64u) {
        int nrows = (int)((cnt - c0 < 64u) ? (cnt - c0) : 64u);
        if (t < 64) {
            int n = worklist[(t < nrows) ? (c0 + t) : c0];  // pad: dup row 0
            rown[t] = n;
            rgminS[t] = gminbuf[n];
            candCnt[t] = 0;
            rpack[t] = ~0ull;
        }
        __syncthreads();

        {   // stage gathered z rows into A-fragment layout
            int r = t & 63, gb = t >> 6;
            int n = rown[r];
            int b = n >> 12, p = n & 4095;
            const float* zp = z + (size_t)b * BSTRIDE + p;
#pragma unroll
            for (int gg = 0; gg < 2; ++gg) {
                int g = (gb << 1) | gg;
                short8 hi8, lo8;
#pragma unroll
                for (int i2 = 0; i2 < 8; ++i2) {
                    float v = zp[(size_t)(8 * g + i2) * DSTRIDE];
                    unsigned short h = f2bf_rne(v);
                    float hf = __uint_as_float((unsigned)h << 16);
                    hi8[i2] = (short)h;
                    lo8[i2] = (short)f2bf_rne(v - hf);
                }
                int rt = r >> 4, s = g >> 2, lane = (r & 15) + 16 * (g & 3);
                *(short8*)&aFrag[rt][s][0][lane][0] = hi8;
                *(short8*)&aFrag[rt][s][1][lane][0] = lo8;
            }
        }
        __syncthreads();

        short8 aH0 = *(const short8*)&aFrag[w][0][0][l][0];
        short8 aH1 = *(const short8*)&aFrag[w][1][0][l][0];
        short8 aL0 = *(const short8*)&aFrag[w][0][1][l][0];
        short8 aL1 = *(const short8*)&aFrag[w][1][1][l][0];

        int rowbase = (w << 4) + ((l >> 4) << 2);
        float rg[4];
#pragma unroll
        for (int r = 0; r < 4; ++r) rg[r] = rgminS[rowbase + r] + 2e-4f;

        for (int ct = 0; ct < 64; ++ct) {
            const unsigned short* bp = cbB + ct * 2048 + (l << 3);
            short8 b0 = *(const short8*)(bp);
            short8 b1 = *(const short8*)(bp + 512);
            short8 b2 = *(const short8*)(bp + 1024);
            short8 b3 = *(const short8*)(bp + 1536);
            float cs = scsq[(ct << 4) + colcode];
            unsigned code = (unsigned)((ct << 4) + colcode);
            f32x4 p = {0.f, 0.f, 0.f, 0.f}, q = {0.f, 0.f, 0.f, 0.f};
            MFMA_DIST(p, q, aH0, aH1, aL0, aL1, b0, b1, b2, b3)
#pragma unroll
            for (int r = 0; r < 4; ++r) {
                float dist = fmaf(-2.f, p[r] + q[r], cs);
                if (dist < rg[r]) {
                    int row = rowbase + r;
                    int pos = atomicAdd(&candCnt[row], 1);
                    if (pos < RF_CAND) candK[row][pos] = (unsigned short)code;
                }
            }
        }
        __syncthreads();

        // ---- fp64 reference-emulated distance on candidates ----
        for (int i = t; i < 64 * RF_CAND; i += 256) {
            int r = i >> 4, sIdx = i & (RF_CAND - 1);
            int cc = candCnt[r];
            if (r < nrows && cc <= RF_CAND && sIdx < cc) {
                unsigned k = candK[r][sIdx];
                int n = rown[r];
                int b = n >> 12, p = n & 4095;
                const float* zp = z + (size_t)b * BSTRIDE + p;
                const float* cp = cb + k * DD;
                double a0 = 0.0, a1 = 0.0, a2 = 0.0, a3 = 0.0;
#pragma unroll
                for (int d = 0; d < DD; d += 4) {
                    a0 = fma((double)zp[(size_t)(d + 0) * DSTRIDE], (double)cp[d + 0], a0);
                    a1 = fma((double)zp[(size_t)(d + 1) * DSTRIDE], (double)cp[d + 1], a1);
                    a2 = fma((double)zp[(size_t)(d + 2) * DSTRIDE], (double)cp[d + 2], a2);
                    a3 = fma((double)zp[(size_t)(d + 3) * DSTRIDE], (double)cp[d + 3], a3);
                }
                double dot = (a0 + a1) + (a2 + a3);
                float twoC = (float)(2.0 * dot);
                float dist = __fsub_rn(__fadd_rn(zsq32[n], csq[k]), twoC);
                unsigned ub = __float_as_uint(dist);
                ub = (ub & 0x80000000u) ? ~ub : (ub | 0x80000000u);
                unsigned long long pk = ((unsigned long long)ub << 32) | k;
                atomicMin(&rpack[r], pk);
            }
        }
        // overflow rows (ultra-rare, adversarial ties): all 1024 codes
        for (int r = 0; r < 64; ++r) {
            if (candCnt[r] > RF_CAND && r < nrows) {
                int n = rown[r];
                int b = n >> 12, p = n & 4095;
                const float* zp = z + (size_t)b * BSTRIDE + p;
                for (unsigned k = (unsigned)t; k < 1024u; k += 256u) {
                    const float* cp = cb + k * DD;
                    double a0 = 0.0, a1 = 0.0, a2 = 0.0, a3 = 0.0;
#pragma unroll
                    for (int d = 0; d < DD; d += 4) {
                        a0 = fma((double)zp[(size_t)(d + 0) * DSTRIDE], (double)cp[d + 0], a0);
                        a1 = fma((double)zp[(size_t)(d + 1) * DSTRIDE], (double)cp[d + 1], a1);
                        a2 = fma((double)zp[(size_t)(d + 2) * DSTRIDE], (double)cp[d + 2], a2);
                        a3 = fma((double)zp[(size_t)(d + 3) * DSTRIDE], (double)cp[d + 3], a3);
                    }
                    double dot = (a0 + a1) + (a2 + a3);
                    float twoC = (float)(2.0 * dot);
                    float dist = __fsub_rn(__fadd_rn(zsq32[n], csq[k]), twoC);
                    unsigned ub = __float_as_uint(dist);
                    ub = (ub & 0x80000000u) ? ~ub : (ub | 0x80000000u);
                    unsigned long long pk = ((unsigned long long)ub << 32) | k;
                    atomicMin(&rpack[r], pk);
                }
            }
        }
        __syncthreads();

        if (t < nrows)
            idxf[rown[t]] = (float)(unsigned)(rpack[t] & 0xFFFFFFFFull);
        __syncthreads();  // before next chunk reuses LDS
    }
}

// -------- gather z_q + loss partial reduction --------
__global__ __launch_bounds__(256) void vq_gather_loss(const float* __restrict__ z,
                                                      const float* __restrict__ cb,
                                                      const float* __restrict__ idxf,
                                                      float* __restrict__ zq_out,
                                                      double* __restrict__ acc) {
    int n = blockIdx.x * 256 + threadIdx.x;
    int b = n >> 12, p = n & 4095;
    const float* zp = z + (size_t)b * BSTRIDE + p;
    float* qp = zq_out + (size_t)b * BSTRIDE + p;
    int k = (int)idxf[n];
    const float* c = cb + k * DD;

    float s = 0.f;
#pragma unroll
    for (int d = 0; d < DD; ++d) {
        float q = c[d];
        float diff = q - zp[(size_t)d * DSTRIDE];
        s = fmaf(diff, diff, s);
        qp[(size_t)d * DSTRIDE] = q;  // z_q_st == z_q numerically
    }

#pragma unroll
    for (int off = 32; off; off >>= 1) s += __shfl_down(s, off, 64);
    __shared__ float partial[4];
    if ((threadIdx.x & 63) == 0) partial[threadIdx.x >> 6] = s;
    __syncthreads();
    if (threadIdx.x == 0) {
        float t = (partial[0] + partial[1]) + (partial[2] + partial[3]);
        atomicAdd(acc, (double)t);
    }
}

__global__ void vq_finalize(const double* __restrict__ acc, float* __restrict__ loss_out) {
    *loss_out = (float)(1.25 * (*acc) / (double)ZQ_ELEMS);
}

extern "C" void kernel_launch(void* const* d_in, const int* in_sizes, int n_in,
                              void* d_out, int out_size, void* d_ws, size_t ws_size,
                              hipStream_t stream) {
    const float* z = (const float*)d_in[0];
    const float* cb = (const float*)d_in[1];
    float* out = (float*)d_out;

    float* zq_out = out;                   // [0, 8388608)
    float* loss_out = out + ZQ_ELEMS;      // [8388608]
    float* idxf_out = out + ZQ_ELEMS + 1;  // [8388609, +131072)

    char* ws = (char*)d_ws;
    double* acc = (double*)ws;
    unsigned* wcount = (unsigned*)(ws + 8);
    float* csq = (float*)(ws + WS_CSQ_OFF);
    float* zsq32 = (float*)(ws + WS_ZSQ_OFF);
    int* worklist = (int*)(ws + WS_WORK_OFF);
    float* gminbuf = (float*)(ws + WS_GMIN_OFF);
    unsigned short* cbB = (unsigned short*)(ws + WS_CBB_OFF);

    hipMemsetAsync(d_ws, 0, 16, stream);   // acc = 0, wcount = 0

    vq_csq<<<KK / 256, 256, 0, stream>>>(cb, csq);
    vq_prep_b<<<KK * DD / 256, 256, 0, stream>>>(cb, cbB);
    vq_zsq<<<ZN / 256, 256, 0, stream>>>(z, zsq32);
    vq_scan<<<ZN / 64, 256, 0, stream>>>(z, cbB, csq, idxf_out, gminbuf, wcount, worklist);
    vq_refine<<<768, 256, 0, stream>>>(z, cbB, cb, csq, zsq32, gminbuf, wcount, worklist, idxf_out);
    vq_gather_loss<<<ZN / 256, 256, 0, stream>>>(z, cb, idxf_out, zq_out, acc);
    vq_finalize<<<1, 1, 0, stream>>>(acc, loss_out);
}